// Round 10
// baseline (335.838 us; speedup 1.0000x reference)
//
#include <hip/hip_runtime.h>
#include <hip/hip_bf16.h>
#include <cstddef>

#define NN    50000
#define NE    800000
#define FIN   256
#define HID   64
#define NH    8
#define F1    512      // NH*HID
#define EMB   128
#define ALPHA 0.2f
#define EPSF  1e-16f
#define NBLK  ((NN + 255) / 256)   // 196

#if defined(__has_builtin)
# if __has_builtin(__builtin_amdgcn_cvt_scalef32_pk_f32_fp4) && __has_builtin(__builtin_amdgcn_cvt_scalef32_pk_fp4_f32)
#  define HAVE_FP4 1
# else
#  define HAVE_FP4 0
# endif
#else
# define HAVE_FP4 0
#endif

typedef __hip_bfloat16 bf16;
typedef __attribute__((ext_vector_type(8))) short short8;
typedef __attribute__((ext_vector_type(4))) float f32x4;
typedef __attribute__((ext_vector_type(2))) float f32x2;

#if HAVE_FP4
typedef uint2 pay_t;            // 16 fp4 = 8 B
#define PAYB1 (F1 / 2)          // 256 B per layer-1 row
#define PAYB2 (EMB / 2)         // 64 B per layer-2 row
#define SINV1 2.0f
#define SINV2 4.0f
#define PSC1  0.5f
#define PSC2  0.25f
#else
typedef uint4 pay_t;            // 16 fp8 = 16 B
#define PAYB1 F1
#define PAYB2 EMB
#define SINV1 1.0f
#define SINV2 1.0f
#define PSC1  1.0f
#define PSC2  1.0f
#endif

__device__ __forceinline__ float eluf(float x){ return x > 0.f ? x : __expf(x) - 1.f; }
__device__ __forceinline__ float lrelu_neg_exp(float s){
    float lr = s > 0.f ? s : ALPHA * s;
    return __expf(-lr);
}
__device__ __forceinline__ float b2f(unsigned u){ return __uint_as_float(u << 16); }

// acc[0..7] (f32x2) += e * payload(q)
__device__ __forceinline__ void fma16pk(f32x2* acc, pay_t q, float e){
    f32x2 e2; e2[0] = e; e2[1] = e;
#if HAVE_FP4
    acc[0] += __builtin_amdgcn_cvt_scalef32_pk_f32_fp4(q.x, 1.0f, 0) * e2;
    acc[1] += __builtin_amdgcn_cvt_scalef32_pk_f32_fp4(q.x, 1.0f, 1) * e2;
    acc[2] += __builtin_amdgcn_cvt_scalef32_pk_f32_fp4(q.x, 1.0f, 2) * e2;
    acc[3] += __builtin_amdgcn_cvt_scalef32_pk_f32_fp4(q.x, 1.0f, 3) * e2;
    acc[4] += __builtin_amdgcn_cvt_scalef32_pk_f32_fp4(q.y, 1.0f, 0) * e2;
    acc[5] += __builtin_amdgcn_cvt_scalef32_pk_f32_fp4(q.y, 1.0f, 1) * e2;
    acc[6] += __builtin_amdgcn_cvt_scalef32_pk_f32_fp4(q.y, 1.0f, 2) * e2;
    acc[7] += __builtin_amdgcn_cvt_scalef32_pk_f32_fp4(q.y, 1.0f, 3) * e2;
#else
    acc[0] += __builtin_amdgcn_cvt_pk_f32_fp8(q.x, false) * e2;
    acc[1] += __builtin_amdgcn_cvt_pk_f32_fp8(q.x, true)  * e2;
    acc[2] += __builtin_amdgcn_cvt_pk_f32_fp8(q.y, false) * e2;
    acc[3] += __builtin_amdgcn_cvt_pk_f32_fp8(q.y, true)  * e2;
    acc[4] += __builtin_amdgcn_cvt_pk_f32_fp8(q.z, false) * e2;
    acc[5] += __builtin_amdgcn_cvt_pk_f32_fp8(q.z, true)  * e2;
    acc[6] += __builtin_amdgcn_cvt_pk_f32_fp8(q.w, false) * e2;
    acc[7] += __builtin_amdgcn_cvt_pk_f32_fp8(q.w, true)  * e2;
#endif
}

// pack two floats as bf16 pair (RNE)
__device__ __forceinline__ unsigned bpack(float a, float b){
    unsigned ua = __float_as_uint(a), ub = __float_as_uint(b);
    ua = (ua + 0x7fffu + ((ua >> 16) & 1)) >> 16;
    ub = (ub + 0x7fffu + ((ub >> 16) & 1)) >> 16;
    return (ua & 0xffffu) | (ub << 16);
}

// ---------------- weight transposes ----------------
__global__ void k_tw1(const float* __restrict__ W1, bf16* __restrict__ Bt1){
    int i = blockIdx.x * 256 + threadIdx.x;
    if (i >= F1 * FIN) return;
    int n = i >> 8, k = i & 255;
    Bt1[i] = __float2bfloat16(W1[(size_t)(n >> 6) * FIN * HID + (size_t)k * HID + (n & 63)]);
}

__global__ void k_tw2(const float* __restrict__ Wo, bf16* __restrict__ WoT){
    int i = blockIdx.x * 256 + threadIdx.x;
    if (i >= EMB * F1) return;
    int n = i >> 9, k = i & 511;
    WoT[i] = __float2bfloat16(Wo[(size_t)k * EMB + n]);
}

// fp8[8] -> packed fp4 payload (layer 2); fallback copy
__global__ void k_q4(const unsigned char* __restrict__ in, unsigned* __restrict__ out,
                     int n8, float sinv){
    int i = blockIdx.x * 256 + threadIdx.x;
    if (i >= n8) return;
    uint2 v = *(const uint2*)(in + (size_t)i * 8);
#if HAVE_FP4
    f32x2 a = __builtin_amdgcn_cvt_pk_f32_fp8(v.x, false);
    f32x2 b = __builtin_amdgcn_cvt_pk_f32_fp8(v.x, true);
    f32x2 c = __builtin_amdgcn_cvt_pk_f32_fp8(v.y, false);
    f32x2 d = __builtin_amdgcn_cvt_pk_f32_fp8(v.y, true);
    unsigned r = 0;
    r = __builtin_amdgcn_cvt_scalef32_pk_fp4_f32(r, a[0] * sinv, a[1] * sinv, 1.0f, 0);
    r = __builtin_amdgcn_cvt_scalef32_pk_fp4_f32(r, b[0] * sinv, b[1] * sinv, 1.0f, 1);
    r = __builtin_amdgcn_cvt_scalef32_pk_fp4_f32(r, c[0] * sinv, c[1] * sinv, 1.0f, 2);
    r = __builtin_amdgcn_cvt_scalef32_pk_fp4_f32(r, d[0] * sinv, d[1] * sinv, 1.0f, 3);
    out[i] = r;
#else
    (void)sinv;
    *(uint2*)((unsigned char*)out + (size_t)i * 8) = v;
#endif
}

// ---------------- CSR build ----------------
__global__ void k_zero(int* p, int n){
    int i = blockIdx.x * 256 + threadIdx.x;
    if (i < n) p[i] = 0;
}

__global__ void k_count(const int* __restrict__ src, int* __restrict__ cnt){
    int e = blockIdx.x * 256 + threadIdx.x;
    if (e < NE) atomicAdd(&cnt[src[e]], 1);
}

__global__ __launch_bounds__(256) void k_bsum(const int* __restrict__ cnt, int* __restrict__ bsum){
    const int b = blockIdx.x, t = threadIdx.x, idx = b * 256 + t;
    int v = (idx < NN) ? cnt[idx] : 0;
#pragma unroll
    for (int o = 1; o < 64; o <<= 1) v += __shfl_xor(v, o);
    __shared__ int ws[4];
    if ((t & 63) == 0) ws[t >> 6] = v;
    __syncthreads();
    if (t == 0) bsum[b] = ws[0] + ws[1] + ws[2] + ws[3];
}

__global__ __launch_bounds__(256) void k_scanb(const int* __restrict__ bsum,
                                               int* __restrict__ boff,
                                               int* __restrict__ rp){
    const int t = threadIdx.x;
    __shared__ int s[256];
    const int v = (t < NBLK) ? bsum[t] : 0;
    s[t] = v;
    __syncthreads();
    for (int o = 1; o < 256; o <<= 1){
        int u = (t >= o) ? s[t - o] : 0;
        __syncthreads();
        s[t] += u;
        __syncthreads();
    }
    if (t < NBLK) boff[t] = s[t] - v;
    if (t == 255) rp[NN] = s[255];
}

__global__ __launch_bounds__(256) void k_rp(const int* __restrict__ cnt,
                                            const int* __restrict__ boff,
                                            int* __restrict__ rp){
    const int b = blockIdx.x, t = threadIdx.x, idx = b * 256 + t;
    const int v = (idx < NN) ? cnt[idx] : 0;
    __shared__ int s[256];
    s[t] = v;
    __syncthreads();
    for (int o = 1; o < 256; o <<= 1){
        int u = (t >= o) ? s[t - o] : 0;
        __syncthreads();
        s[t] += u;
        __syncthreads();
    }
    if (idx < NN) rp[idx] = boff[b] + s[t] - v;
}

__global__ void k_scatter(const int* __restrict__ src, const int* __restrict__ dst,
                          const int* __restrict__ rp, int* __restrict__ cur,
                          int* __restrict__ sdst, int* __restrict__ ssrc){
    int e = blockIdx.x * 256 + threadIdx.x;
    if (e < NE){
        int s = src[e];
        int p = atomicAdd(&cur[s], 1);
        sdst[rp[s] + p] = dst[e];
        ssrc[rp[s] + p] = s;
    }
}

// ---------------- per-CSR-position attention weights, all 8 heads ----------------
__global__ void k_ee(const int* __restrict__ ssrc, const int* __restrict__ sdst,
                     const float* __restrict__ s11, const float* __restrict__ s12,
                     unsigned short* __restrict__ ee8b){
    int i = blockIdx.x * 256 + threadIdx.x;
    if (i >= NE) return;
    int s = ssrc[i], d = sdst[i];
    const float* ps = s11 + (size_t)s * NH;
    const float* pd = s12 + (size_t)d * NH;
    float e[8];
#pragma unroll
    for (int h = 0; h < 8; h++) e[h] = lrelu_neg_exp(ps[h] + pd[h]);
    uint4 o;
    o.x = bpack(e[0], e[1]); o.y = bpack(e[2], e[3]);
    o.z = bpack(e[4], e[5]); o.w = bpack(e[6], e[7]);
    *(uint4*)(ee8b + (size_t)i * 8) = o;
}

// ---------------- GEMM1: A = f32 x (converted in staging), B = Bt1 bf16, C = fp8 ----
__global__ __launch_bounds__(256) void k_gemm1f(const float* __restrict__ A,
                                                const bf16* __restrict__ B,
                                                unsigned char* __restrict__ C){
    constexpr int K = FIN, N = F1;
    constexpr int LDT = 40;
    __shared__ __align__(16) bf16 As[128 * LDT];
    __shared__ __align__(16) bf16 Bs[128 * LDT];
    const int t = threadIdx.x;
    const int lane = t & 63, wid = t >> 6;
    const int m0 = blockIdx.x * 128, n0 = blockIdx.y * 128;
    const int r0 = t >> 2, u0 = t & 3;
    const int r1 = r0 + 64;
    const int rb = (wid & 1) * 64, cb = (wid >> 1) * 64;
    const int fr = lane & 15, fk = (lane >> 4) * 8;

    f32x4 acc[4][4];
#pragma unroll
    for (int i = 0; i < 4; i++)
#pragma unroll
        for (int j = 0; j < 4; j++) acc[i][j] = (f32x4)(0.f);

    for (int k0 = 0; k0 < K; k0 += 32){
        const int ga0 = m0 + r0, ga1 = m0 + r1;
        float4 a0a = make_float4(0,0,0,0), a0b = a0a, a1a = a0a, a1b = a0a;
        if (ga0 < NN){
            const float* p = A + (size_t)ga0 * K + k0 + u0 * 8;
            a0a = *(const float4*)p; a0b = *(const float4*)(p + 4);
        }
        if (ga1 < NN){
            const float* p = A + (size_t)ga1 * K + k0 + u0 * 8;
            a1a = *(const float4*)p; a1b = *(const float4*)(p + 4);
        }
        uint4 av0, av1;
        av0.x = bpack(a0a.x, a0a.y); av0.y = bpack(a0a.z, a0a.w);
        av0.z = bpack(a0b.x, a0b.y); av0.w = bpack(a0b.z, a0b.w);
        av1.x = bpack(a1a.x, a1a.y); av1.y = bpack(a1a.z, a1a.w);
        av1.z = bpack(a1b.x, a1b.y); av1.w = bpack(a1b.z, a1b.w);
        uint4 bv0 = *(const uint4*)(B + (size_t)(n0 + r0) * K + k0 + u0 * 8);
        uint4 bv1 = *(const uint4*)(B + (size_t)(n0 + r1) * K + k0 + u0 * 8);
        __syncthreads();
        *(uint4*)(As + r0 * LDT + u0 * 8) = av0;
        *(uint4*)(As + r1 * LDT + u0 * 8) = av1;
        *(uint4*)(Bs + r0 * LDT + u0 * 8) = bv0;
        *(uint4*)(Bs + r1 * LDT + u0 * 8) = bv1;
        __syncthreads();
        short8 af[4], bf_[4];
#pragma unroll
        for (int i = 0; i < 4; i++){
            af[i]  = *(const short8*)(As + (rb + i * 16 + fr) * LDT + fk);
            bf_[i] = *(const short8*)(Bs + (cb + i * 16 + fr) * LDT + fk);
        }
#pragma unroll
        for (int i = 0; i < 4; i++)
#pragma unroll
            for (int j = 0; j < 4; j++)
                acc[i][j] = __builtin_amdgcn_mfma_f32_16x16x32_bf16(af[i], bf_[j], acc[i][j], 0, 0, 0);
    }
    const int crow = m0 + rb + (lane >> 4) * 4;
    const int ccol = n0 + cb + (lane & 15);
#pragma unroll
    for (int i = 0; i < 4; i++)
#pragma unroll
        for (int j = 0; j < 4; j++)
#pragma unroll
            for (int v = 0; v < 4; v++){
                int row = crow + i * 16 + v;
                if (row < NN){
                    float val = acc[i][j][v];
                    unsigned r = __builtin_amdgcn_cvt_pk_fp8_f32(val, val, 0u, false);
                    C[(size_t)row * N + ccol + j * 16] = (unsigned char)(r & 0xffu);
                }
            }
}

// ---------------- GEMM2: bf16 A, fp8 out ----------------
template<int K>
__global__ __launch_bounds__(256) void k_mgemm(const bf16* __restrict__ A,
                                               const bf16* __restrict__ B,
                                               unsigned char* __restrict__ C,
                                               int N){
    constexpr int LDT = 40;
    __shared__ __align__(16) bf16 As[128 * LDT];
    __shared__ __align__(16) bf16 Bs[128 * LDT];
    const int t = threadIdx.x;
    const int lane = t & 63, wid = t >> 6;
    const int m0 = blockIdx.x * 128, n0 = blockIdx.y * 128;
    const int r0 = t >> 2, u0 = t & 3;
    const int r1 = r0 + 64;
    const int rb = (wid & 1) * 64, cb = (wid >> 1) * 64;
    const int fr = lane & 15, fk = (lane >> 4) * 8;

    f32x4 acc[4][4];
#pragma unroll
    for (int i = 0; i < 4; i++)
#pragma unroll
        for (int j = 0; j < 4; j++) acc[i][j] = (f32x4)(0.f);

    for (int k0 = 0; k0 < K; k0 += 32){
        const int ga0 = m0 + r0, ga1 = m0 + r1;
        uint4 av0 = (ga0 < NN) ? *(const uint4*)(A + (size_t)ga0 * K + k0 + u0 * 8)
                               : make_uint4(0, 0, 0, 0);
        uint4 av1 = (ga1 < NN) ? *(const uint4*)(A + (size_t)ga1 * K + k0 + u0 * 8)
                               : make_uint4(0, 0, 0, 0);
        uint4 bv0 = *(const uint4*)(B + (size_t)(n0 + r0) * K + k0 + u0 * 8);
        uint4 bv1 = *(const uint4*)(B + (size_t)(n0 + r1) * K + k0 + u0 * 8);
        __syncthreads();
        *(uint4*)(As + r0 * LDT + u0 * 8) = av0;
        *(uint4*)(As + r1 * LDT + u0 * 8) = av1;
        *(uint4*)(Bs + r0 * LDT + u0 * 8) = bv0;
        *(uint4*)(Bs + r1 * LDT + u0 * 8) = bv1;
        __syncthreads();
        short8 af[4], bf_[4];
#pragma unroll
        for (int i = 0; i < 4; i++){
            af[i]  = *(const short8*)(As + (rb + i * 16 + fr) * LDT + fk);
            bf_[i] = *(const short8*)(Bs + (cb + i * 16 + fr) * LDT + fk);
        }
#pragma unroll
        for (int i = 0; i < 4; i++)
#pragma unroll
            for (int j = 0; j < 4; j++)
                acc[i][j] = __builtin_amdgcn_mfma_f32_16x16x32_bf16(af[i], bf_[j], acc[i][j], 0, 0, 0);
    }
    const int crow = m0 + rb + (lane >> 4) * 4;
    const int ccol = n0 + cb + (lane & 15);
#pragma unroll
    for (int i = 0; i < 4; i++)
#pragma unroll
        for (int j = 0; j < 4; j++)
#pragma unroll
            for (int v = 0; v < 4; v++){
                int row = crow + i * 16 + v;
                if (row < NN){
                    float val = acc[i][j][v];
                    unsigned r = __builtin_amdgcn_cvt_pk_fp8_f32(val, val, 0u, false);
                    C[(size_t)row * N + ccol + j * 16] = (unsigned char)(r & 0xffu);
                }
            }
}

// ---------------- fused: layer-1 scalars + fp4 payload encode ----------------
__global__ void k_s1q(const unsigned char* __restrict__ h1q, const float* __restrict__ a1,
                      float* __restrict__ s11, float* __restrict__ s12,
                      unsigned char* __restrict__ pay){
    int idx = blockIdx.x * 256 + threadIdx.x;
    if (idx >= NN * NH) return;
    int n = idx >> 3, h = idx & 7;
    const uint4* hp = (const uint4*)(h1q + (size_t)n * F1 + h * HID);
    const float* a  = a1 + (size_t)h * 2 * HID;
    float d1 = 0.f, d2 = 0.f;
    float f[64];
#pragma unroll
    for (int u = 0; u < 4; u++){
        uint4 q = hp[u];
        int j = u * 16;
        f32x2 p;
        p = __builtin_amdgcn_cvt_pk_f32_fp8(q.x, false); f[j+0]=p[0];  f[j+1]=p[1];
        p = __builtin_amdgcn_cvt_pk_f32_fp8(q.x, true);  f[j+2]=p[0];  f[j+3]=p[1];
        p = __builtin_amdgcn_cvt_pk_f32_fp8(q.y, false); f[j+4]=p[0];  f[j+5]=p[1];
        p = __builtin_amdgcn_cvt_pk_f32_fp8(q.y, true);  f[j+6]=p[0];  f[j+7]=p[1];
        p = __builtin_amdgcn_cvt_pk_f32_fp8(q.z, false); f[j+8]=p[0];  f[j+9]=p[1];
        p = __builtin_amdgcn_cvt_pk_f32_fp8(q.z, true);  f[j+10]=p[0]; f[j+11]=p[1];
        p = __builtin_amdgcn_cvt_pk_f32_fp8(q.w, false); f[j+12]=p[0]; f[j+13]=p[1];
        p = __builtin_amdgcn_cvt_pk_f32_fp8(q.w, true);  f[j+14]=p[0]; f[j+15]=p[1];
    }
#pragma unroll
    for (int j = 0; j < 64; j++){
        d1 += f[j] * a[j];
        d2 += f[j] * a[HID + j];
    }
    s11[idx] = d1;
    s12[idx] = d2;
#if HAVE_FP4
    unsigned w8[8];
#pragma unroll
    for (int u = 0; u < 8; u++){
        unsigned rr = 0;
        int j = u * 8;
        rr = __builtin_amdgcn_cvt_scalef32_pk_fp4_f32(rr, f[j+0]*SINV1, f[j+1]*SINV1, 1.0f, 0);
        rr = __builtin_amdgcn_cvt_scalef32_pk_fp4_f32(rr, f[j+2]*SINV1, f[j+3]*SINV1, 1.0f, 1);
        rr = __builtin_amdgcn_cvt_scalef32_pk_fp4_f32(rr, f[j+4]*SINV1, f[j+5]*SINV1, 1.0f, 2);
        rr = __builtin_amdgcn_cvt_scalef32_pk_fp4_f32(rr, f[j+6]*SINV1, f[j+7]*SINV1, 1.0f, 3);
        w8[u] = rr;
    }
    uint4* op = (uint4*)(pay + (size_t)n * PAYB1 + h * (HID / 2));
    uint4 o0, o1;
    o0.x = w8[0]; o0.y = w8[1]; o0.z = w8[2]; o0.w = w8[3];
    o1.x = w8[4]; o1.y = w8[5]; o1.z = w8[6]; o1.w = w8[7];
    op[0] = o0; op[1] = o1;
#else
    uint4* op = (uint4*)(pay + (size_t)n * PAYB1 + h * HID);
    op[0] = hp[0]; op[1] = hp[1]; op[2] = hp[2]; op[3] = hp[3];
#endif
}

// ---------------- layer-1 aggregation: shallow dependency graph, 16 loads in flight ----
__global__ __launch_bounds__(256) void k_agg1(const unsigned char* __restrict__ hq,
                                              const unsigned short* __restrict__ ee8b,
                                              const int* __restrict__ rp,
                                              const int* __restrict__ sdst,
                                              bf16* __restrict__ x1){
    const int t = threadIdx.x, lane = t & 63, w = t >> 6;
    const int n = blockIdx.x * 4 + w;
    const int l32 = lane & 31;
    const int half = lane >> 5;        // which edge of each pair
    const int hf = l32 >> 2;           // head of owned 16 features
    const int eslot = lane >> 3;       // denominator role: edge sub-slot
    f32x2 acc[8];
#pragma unroll
    for (int i = 0; i < 8; i++){ acc[i][0] = 0.f; acc[i][1] = 0.f; }
    float dedp = 0.f;
    const int start = rp[n], end = rp[n + 1];
    const unsigned char* __restrict__ hl = hq + (size_t)l32 * (PAYB1 / 32);
    for (int c0 = start; c0 < end; c0 += 64){
        const int m = min(64, end - c0);
        int dreg = (lane < m) ? sdst[c0 + lane] : 0;
        // denominator: coalesced ee reads (lane -> edge c0+g*8+(lane>>3), head lane&7)
        for (int g = 0; g * 8 < m; g++){
            unsigned short eu = ee8b[(size_t)(c0 + g * 8) * 8 + lane];
            dedp += (g * 8 + eslot < m) ? b2f(eu) : 0.f;
        }
        // pairs: 16 edges per sweep, all 16 loads issued before the FMA chain
        for (int j = 0; j < m; j += 16){
            int dj[8]; unsigned short eu[8]; pay_t q[8];
#pragma unroll
            for (int p = 0; p < 8; p++){
                const int e2 = j + 2 * p + half;            // <= 63 always
                dj[p] = __shfl(dreg, e2);
                eu[p] = ee8b[(size_t)(c0 + e2) * 8 + hf];
                q[p]  = *(const pay_t*)(hl + (size_t)dj[p] * PAYB1);
            }
#pragma unroll
            for (int p = 0; p < 8; p++){
                const int e2 = j + 2 * p + half;
                const float e = (e2 < m) ? b2f(eu[p]) : 0.f;
                fma16pk(acc, q[p], e);
            }
        }
    }
    // denominator: reduce over edge-slots (lane bits 3..5); lane l holds ded[l&7]
    dedp += __shfl_xor(dedp, 8);
    dedp += __shfl_xor(dedp, 16);
    dedp += __shfl_xor(dedp, 32);
    // combine the two edge-halves' accumulators
#pragma unroll
    for (int i = 0; i < 8; i++){
        acc[i][0] += __shfl_xor(acc[i][0], 32);
        acc[i][1] += __shfl_xor(acc[i][1], 32);
    }
    float ded = __shfl(dedp, hf);
    const float inv = PSC1 / (ded + EPSF);
    if (half == 0){
        float o[16];
#pragma unroll
        for (int i = 0; i < 8; i++){
            o[2 * i]     = eluf(acc[i][0] * inv);
            o[2 * i + 1] = eluf(acc[i][1] * inv);
        }
        uint4 ov0, ov1;
        ov0.x = bpack(o[0], o[1]);   ov0.y = bpack(o[2], o[3]);
        ov0.z = bpack(o[4], o[5]);   ov0.w = bpack(o[6], o[7]);
        ov1.x = bpack(o[8], o[9]);   ov1.y = bpack(o[10], o[11]);
        ov1.z = bpack(o[12], o[13]); ov1.w = bpack(o[14], o[15]);
        bf16* xp = x1 + (size_t)n * F1 + l32 * 16;
        *(uint4*)xp = ov0;
        *(uint4*)(xp + 8) = ov1;
    }
}

// ---------------- per-node attention scalars, layer 2 (fp8 h2) ----------------
__global__ void k_s2(const unsigned char* __restrict__ h2q, const float* __restrict__ ao,
                     float* __restrict__ s21, float* __restrict__ s22){
    int n = blockIdx.x * 256 + threadIdx.x;
    if (n >= NN) return;
    const uint4* hp = (const uint4*)(h2q + (size_t)n * EMB);
    float d1 = 0.f, d2 = 0.f;
#pragma unroll
    for (int u = 0; u < 8; u++){
        uint4 q = hp[u];
        int j = u * 16;
#define S2(w, o) { f32x2 p0 = __builtin_amdgcn_cvt_pk_f32_fp8((w), false); \
                   f32x2 p1 = __builtin_amdgcn_cvt_pk_f32_fp8((w), true); \
                   d1 += p0[0]*ao[(o)] + p0[1]*ao[(o)+1] + p1[0]*ao[(o)+2] + p1[1]*ao[(o)+3]; \
                   d2 += p0[0]*ao[EMB+(o)] + p0[1]*ao[EMB+(o)+1] + p1[0]*ao[EMB+(o)+2] + p1[1]*ao[EMB+(o)+3]; }
        S2(q.x, j) S2(q.y, j + 4) S2(q.z, j + 8) S2(q.w, j + 12)
#undef S2
    }
    s21[n] = d1;
    s22[n] = d2;
}

// ---------------- layer-2 aggregation ----------------
__global__ __launch_bounds__(256) void k_agg2(const unsigned char* __restrict__ hq,
                                              const float* __restrict__ s21,
                                              const float* __restrict__ s22,
                                              const int* __restrict__ rp,
                                              const int* __restrict__ sdst,
                                              float* __restrict__ den2,
                                              float* __restrict__ out0){
    const int t = threadIdx.x, lane = t & 63, w = t >> 6;
    const int n = blockIdx.x * 4 + w;
    const int slot = lane >> 3;        // edge sub-index 0..7
    const int fpos = lane & 7;         // features fpos*16 .. +15
    const float s1v = s21[n];
    f32x2 acc[8];
#pragma unroll
    for (int i = 0; i < 8; i++){ acc[i][0] = 0.f; acc[i][1] = 0.f; }
    float dedp = 0.f;
    const int start = rp[n], end = rp[n + 1];
    const unsigned char* __restrict__ hl = hq + (size_t)fpos * (PAYB2 / 8);
    for (int c0 = start; c0 < end; c0 += 64){
        const int m = min(64, end - c0);
        int dreg = (lane < m) ? sdst[c0 + lane] : 0;
        float ev = (lane < m) ? lrelu_neg_exp(s1v + s22[dreg]) : 0.f;
        dedp += ev;
        for (int j = 0; j < m; j += 8){
            const int ei = j + slot;
            const float e = __shfl(ev, ei);
            const int   d = __shfl(dreg, ei);
            pay_t q = *(const pay_t*)(hl + (size_t)d * PAYB2);
            fma16pk(acc, q, e);
        }
    }
#pragma unroll
    for (int o = 1; o <= 32; o <<= 1) dedp += __shfl_xor(dedp, o);
#pragma unroll
    for (int o = 8; o <= 32; o <<= 1)
#pragma unroll
        for (int i = 0; i < 8; i++){
            acc[i][0] += __shfl_xor(acc[i][0], o);
            acc[i][1] += __shfl_xor(acc[i][1], o);
        }
    const float den = dedp + EPSF;
    if (slot == 0){
        const float inv = PSC2 / den;
        float* op = out0 + (size_t)n * EMB + fpos * 16;
#pragma unroll
        for (int u = 0; u < 4; u++){
            float4 ov;
            ov.x = eluf(acc[2 * u][0] * inv);
            ov.y = eluf(acc[2 * u][1] * inv);
            ov.z = eluf(acc[2 * u + 1][0] * inv);
            ov.w = eluf(acc[2 * u + 1][1] * inv);
            *(float4*)(op + u * 4) = ov;
        }
        if (lane == 0) den2[n] = den;
    }
}

// ---------------- fused: edge_index copy + att_out ----------------
__global__ void k_att_edge(const int* __restrict__ ei,
                           const float* __restrict__ s21, const float* __restrict__ s22,
                           const float* __restrict__ den2,
                           float* __restrict__ outE, float* __restrict__ outA){
    int i = blockIdx.x * 256 + threadIdx.x;
    if (i < 2 * NE) outE[i] = (float)ei[i];
    if (i < NE){
        int s = ei[i], d = ei[NE + i];
        float ee = lrelu_neg_exp(s21[s] + s22[d]);
        outA[i] = ee / den2[s];
    }
}

// ---------------- launch ----------------
extern "C" void kernel_launch(void* const* d_in, const int* in_sizes, int n_in,
                              void* d_out, int out_size, void* d_ws, size_t ws_size,
                              hipStream_t stream){
    const float* x  = (const float*)d_in[0];
    const int*   ei = (const int*)d_in[1];
    const float* W1 = (const float*)d_in[2];
    const float* a1 = (const float*)d_in[3];
    const float* Wo = (const float*)d_in[4];
    const float* ao = (const float*)d_in[5];
    float* out = (float*)d_out;
    const int* src = ei;
    const int* dst = ei + NE;

    char* w = (char*)d_ws;
    auto alloc = [&](size_t bytes) -> char* {
        char* p = w;
        w += (bytes + 255) & ~(size_t)255;
        return p;
    };
    unsigned char* h1pay = (unsigned char*)alloc((size_t)NN * F1);       // 25.6 MB
    bf16*  x1   = (bf16*) alloc((size_t)NN * F1 * 2);                    // 51.2 MB
    unsigned char* h1q = (unsigned char*)alloc((size_t)NN * F1);         // 25.6 MB
    unsigned char* h2q = (unsigned char*)alloc((size_t)NN * EMB);        // 6.4 MB
    unsigned short* ee8b = (unsigned short*)alloc(((size_t)NE + 64) * 8 * 2); // 12.8 MB
    bf16*  Bt1  = (bf16*) alloc((size_t)F1 * FIN * 2);
    bf16*  WoT  = (bf16*) alloc((size_t)EMB * F1 * 2);
    float* s11  = (float*)alloc((size_t)NN * NH * 4);
    float* s12  = (float*)alloc((size_t)NN * NH * 4);
    float* s21  = (float*)alloc((size_t)NN * 4);
    float* s22  = (float*)alloc((size_t)NN * 4);
    float* den2 = (float*)alloc((size_t)NN * 4);
    int*   cnt2 = (int*)  alloc((size_t)2 * NN * 4);
    int*   rp   = (int*)  alloc((size_t)(NN + 1) * 4);
    int*   sdst = (int*)  alloc((size_t)NE * 4);
    int*   ssrc = (int*)  alloc((size_t)NE * 4);
    int*   bsum = (int*)  alloc((size_t)NBLK * 4);
    int*   boff = (int*)  alloc((size_t)NBLK * 4);
    int*   cnt = cnt2;
    int*   cur = cnt2 + NN;
    unsigned char* h2pay = (unsigned char*)x1;   // x1 dead after gemm2

    // weight transposes
    k_tw1<<<(F1 * FIN + 255) / 256, 256, 0, stream>>>(W1, Bt1);
    k_tw2<<<(EMB * F1 + 255) / 256, 256, 0, stream>>>(Wo, WoT);

    // CSR build
    k_zero   <<<(2 * NN + 255) / 256, 256, 0, stream>>>(cnt2, 2 * NN);
    k_count  <<<(NE + 255) / 256,     256, 0, stream>>>(src, cnt);
    k_bsum   <<<NBLK,                 256, 0, stream>>>(cnt, bsum);
    k_scanb  <<<1,                    256, 0, stream>>>(bsum, boff, rp);
    k_rp     <<<NBLK,                 256, 0, stream>>>(cnt, boff, rp);
    k_scatter<<<(NE + 255) / 256,     256, 0, stream>>>(src, dst, rp, cur, sdst, ssrc);

    // layer 1
    k_gemm1f<<<dim3((NN + 127) / 128, F1 / 128), 256, 0, stream>>>(x, Bt1, h1q);
    k_s1q <<<(NN * NH + 255) / 256, 256, 0, stream>>>(h1q, a1, s11, s12, h1pay);
    k_ee  <<<(NE + 255) / 256, 256, 0, stream>>>(ssrc, sdst, s11, s12, ee8b);
    k_agg1<<<NN / 4, 256, 0, stream>>>(h1pay, ee8b, rp, sdst, x1);

    // layer 2
    k_mgemm<F1><<<dim3((NN + 127) / 128, EMB / 128), 256, 0, stream>>>(x1, WoT, h2q, EMB);
    k_q4  <<<(NN * EMB / 8 + 255) / 256, 256, 0, stream>>>(h2q, (unsigned*)h2pay, NN * EMB / 8, SINV2);
    k_s2  <<<(NN + 255) / 256, 256, 0, stream>>>(h2q, ao, s21, s22);
    k_agg2<<<NN / 4, 256, 0, stream>>>(h2pay, s21, s22, rp, sdst, den2, out);

    // outputs 1 & 2
    k_att_edge<<<(2 * NE + 255) / 256, 256, 0, stream>>>(ei, s21, s22, den2,
                                                         out + (size_t)NN * EMB,
                                                         out + (size_t)NN * EMB + 2 * NE);
}

// Round 11
// 319.705 us; speedup vs baseline: 1.0505x; 1.0505x over previous
//
#include <hip/hip_runtime.h>
#include <hip/hip_bf16.h>
#include <cstddef>

#define NN    50000
#define NE    800000
#define FIN   256
#define HID   64
#define NH    8
#define F1    512      // NH*HID
#define EMB   128
#define ALPHA 0.2f
#define EPSF  1e-16f
#define NBLK  ((NN + 255) / 256)   // 196

#if defined(__has_builtin)
# if __has_builtin(__builtin_amdgcn_cvt_scalef32_pk_f32_fp4) && __has_builtin(__builtin_amdgcn_cvt_scalef32_pk_fp4_f32)
#  define HAVE_FP4 1
# else
#  define HAVE_FP4 0
# endif
#else
# define HAVE_FP4 0
#endif

typedef __hip_bfloat16 bf16;
typedef __attribute__((ext_vector_type(8))) short short8;
typedef __attribute__((ext_vector_type(4))) float f32x4;
typedef __attribute__((ext_vector_type(2))) float f32x2;

#if HAVE_FP4
typedef uint2 pay_t;            // 16 fp4 = 8 B
#define PAYB1 (F1 / 2)          // 256 B per layer-1 row
#define PAYB2 (EMB / 2)         // 64 B per layer-2 row
#define SINV1 2.0f
#define SINV2 4.0f
#define PSC1  0.5f
#define PSC2  0.25f
#else
typedef uint4 pay_t;            // 16 fp8 = 16 B
#define PAYB1 F1
#define PAYB2 EMB
#define SINV1 1.0f
#define SINV2 1.0f
#define PSC1  1.0f
#define PSC2  1.0f
#endif

__device__ __forceinline__ float eluf(float x){ return x > 0.f ? x : __expf(x) - 1.f; }
__device__ __forceinline__ float lrelu_neg_exp(float s){
    float lr = s > 0.f ? s : ALPHA * s;
    return __expf(-lr);
}
__device__ __forceinline__ float b2f(unsigned u){ return __uint_as_float(u << 16); }

// acc[0..7] (f32x2) += e * payload(q)
__device__ __forceinline__ void fma16pk(f32x2* acc, pay_t q, float e){
    f32x2 e2; e2[0] = e; e2[1] = e;
#if HAVE_FP4
    acc[0] += __builtin_amdgcn_cvt_scalef32_pk_f32_fp4(q.x, 1.0f, 0) * e2;
    acc[1] += __builtin_amdgcn_cvt_scalef32_pk_f32_fp4(q.x, 1.0f, 1) * e2;
    acc[2] += __builtin_amdgcn_cvt_scalef32_pk_f32_fp4(q.x, 1.0f, 2) * e2;
    acc[3] += __builtin_amdgcn_cvt_scalef32_pk_f32_fp4(q.x, 1.0f, 3) * e2;
    acc[4] += __builtin_amdgcn_cvt_scalef32_pk_f32_fp4(q.y, 1.0f, 0) * e2;
    acc[5] += __builtin_amdgcn_cvt_scalef32_pk_f32_fp4(q.y, 1.0f, 1) * e2;
    acc[6] += __builtin_amdgcn_cvt_scalef32_pk_f32_fp4(q.y, 1.0f, 2) * e2;
    acc[7] += __builtin_amdgcn_cvt_scalef32_pk_f32_fp4(q.y, 1.0f, 3) * e2;
#else
    acc[0] += __builtin_amdgcn_cvt_pk_f32_fp8(q.x, false) * e2;
    acc[1] += __builtin_amdgcn_cvt_pk_f32_fp8(q.x, true)  * e2;
    acc[2] += __builtin_amdgcn_cvt_pk_f32_fp8(q.y, false) * e2;
    acc[3] += __builtin_amdgcn_cvt_pk_f32_fp8(q.y, true)  * e2;
    acc[4] += __builtin_amdgcn_cvt_pk_f32_fp8(q.z, false) * e2;
    acc[5] += __builtin_amdgcn_cvt_pk_f32_fp8(q.z, true)  * e2;
    acc[6] += __builtin_amdgcn_cvt_pk_f32_fp8(q.w, false) * e2;
    acc[7] += __builtin_amdgcn_cvt_pk_f32_fp8(q.w, true)  * e2;
#endif
}

// pack two floats as bf16 pair (RNE)
__device__ __forceinline__ unsigned bpack(float a, float b){
    unsigned ua = __float_as_uint(a), ub = __float_as_uint(b);
    ua = (ua + 0x7fffu + ((ua >> 16) & 1)) >> 16;
    ub = (ub + 0x7fffu + ((ub >> 16) & 1)) >> 16;
    return (ua & 0xffffu) | (ub << 16);
}

// ---------------- weight transposes ----------------
__global__ void k_tw1(const float* __restrict__ W1, bf16* __restrict__ Bt1){
    int i = blockIdx.x * 256 + threadIdx.x;
    if (i >= F1 * FIN) return;
    int n = i >> 8, k = i & 255;
    Bt1[i] = __float2bfloat16(W1[(size_t)(n >> 6) * FIN * HID + (size_t)k * HID + (n & 63)]);
}

__global__ void k_tw2(const float* __restrict__ Wo, bf16* __restrict__ WoT){
    int i = blockIdx.x * 256 + threadIdx.x;
    if (i >= EMB * F1) return;
    int n = i >> 9, k = i & 511;
    WoT[i] = __float2bfloat16(Wo[(size_t)k * EMB + n]);
}

// fp8[8] -> packed fp4 payload (layer 2); fallback copy
__global__ void k_q4(const unsigned char* __restrict__ in, unsigned* __restrict__ out,
                     int n8, float sinv){
    int i = blockIdx.x * 256 + threadIdx.x;
    if (i >= n8) return;
    uint2 v = *(const uint2*)(in + (size_t)i * 8);
#if HAVE_FP4
    f32x2 a = __builtin_amdgcn_cvt_pk_f32_fp8(v.x, false);
    f32x2 b = __builtin_amdgcn_cvt_pk_f32_fp8(v.x, true);
    f32x2 c = __builtin_amdgcn_cvt_pk_f32_fp8(v.y, false);
    f32x2 d = __builtin_amdgcn_cvt_pk_f32_fp8(v.y, true);
    unsigned r = 0;
    r = __builtin_amdgcn_cvt_scalef32_pk_fp4_f32(r, a[0] * sinv, a[1] * sinv, 1.0f, 0);
    r = __builtin_amdgcn_cvt_scalef32_pk_fp4_f32(r, b[0] * sinv, b[1] * sinv, 1.0f, 1);
    r = __builtin_amdgcn_cvt_scalef32_pk_fp4_f32(r, c[0] * sinv, c[1] * sinv, 1.0f, 2);
    r = __builtin_amdgcn_cvt_scalef32_pk_fp4_f32(r, d[0] * sinv, d[1] * sinv, 1.0f, 3);
    out[i] = r;
#else
    (void)sinv;
    *(uint2*)((unsigned char*)out + (size_t)i * 8) = v;
#endif
}

// ---------------- CSR build ----------------
__global__ void k_zero(int* p, int n){
    int i = blockIdx.x * 256 + threadIdx.x;
    if (i < n) p[i] = 0;
}

__global__ void k_count(const int* __restrict__ src, int* __restrict__ cnt){
    int e = blockIdx.x * 256 + threadIdx.x;
    if (e < NE) atomicAdd(&cnt[src[e]], 1);
}

__global__ __launch_bounds__(256) void k_bsum(const int* __restrict__ cnt, int* __restrict__ bsum){
    const int b = blockIdx.x, t = threadIdx.x, idx = b * 256 + t;
    int v = (idx < NN) ? cnt[idx] : 0;
#pragma unroll
    for (int o = 1; o < 64; o <<= 1) v += __shfl_xor(v, o);
    __shared__ int ws[4];
    if ((t & 63) == 0) ws[t >> 6] = v;
    __syncthreads();
    if (t == 0) bsum[b] = ws[0] + ws[1] + ws[2] + ws[3];
}

__global__ __launch_bounds__(256) void k_scanb(const int* __restrict__ bsum,
                                               int* __restrict__ boff,
                                               int* __restrict__ rp){
    const int t = threadIdx.x;
    __shared__ int s[256];
    const int v = (t < NBLK) ? bsum[t] : 0;
    s[t] = v;
    __syncthreads();
    for (int o = 1; o < 256; o <<= 1){
        int u = (t >= o) ? s[t - o] : 0;
        __syncthreads();
        s[t] += u;
        __syncthreads();
    }
    if (t < NBLK) boff[t] = s[t] - v;
    if (t == 255) rp[NN] = s[255];
}

__global__ __launch_bounds__(256) void k_rp(const int* __restrict__ cnt,
                                            const int* __restrict__ boff,
                                            int* __restrict__ rp){
    const int b = blockIdx.x, t = threadIdx.x, idx = b * 256 + t;
    const int v = (idx < NN) ? cnt[idx] : 0;
    __shared__ int s[256];
    s[t] = v;
    __syncthreads();
    for (int o = 1; o < 256; o <<= 1){
        int u = (t >= o) ? s[t - o] : 0;
        __syncthreads();
        s[t] += u;
        __syncthreads();
    }
    if (idx < NN) rp[idx] = boff[b] + s[t] - v;
}

// ---- fused scatter + layer-1 edge attention weights (s,d,pos in registers) ----
__global__ void k_scatter_ee(const int* __restrict__ src, const int* __restrict__ dst,
                             const int* __restrict__ rp, int* __restrict__ cur,
                             const float* __restrict__ s11, const float* __restrict__ s12,
                             int* __restrict__ sdst, int* __restrict__ ssrc,
                             unsigned short* __restrict__ ee8b){
    int e = blockIdx.x * 256 + threadIdx.x;
    if (e >= NE) return;
    int s = src[e], d = dst[e];
    int p = atomicAdd(&cur[s], 1);
    int pos = rp[s] + p;
    sdst[pos] = d;
    ssrc[pos] = s;
    const float* ps = s11 + (size_t)s * NH;
    const float* pd = s12 + (size_t)d * NH;
    float w[8];
#pragma unroll
    for (int h = 0; h < 8; h++) w[h] = lrelu_neg_exp(ps[h] + pd[h]);
    uint4 o;
    o.x = bpack(w[0], w[1]); o.y = bpack(w[2], w[3]);
    o.z = bpack(w[4], w[5]); o.w = bpack(w[6], w[7]);
    *(uint4*)(ee8b + (size_t)pos * 8) = o;
}

// ---- layer-2 edge weights, streaming (CSR order) ----
__global__ void k_ee2(const int* __restrict__ ssrc, const int* __restrict__ sdst,
                      const float* __restrict__ s21, const float* __restrict__ s22,
                      float* __restrict__ ee2){
    int i = blockIdx.x * 256 + threadIdx.x;
    if (i >= NE) return;
    ee2[i] = lrelu_neg_exp(s21[ssrc[i]] + s22[sdst[i]]);
}

// ---------------- GEMM1: A = f32 x (converted in staging), B = Bt1 bf16, C = fp8 ----
__global__ __launch_bounds__(256) void k_gemm1f(const float* __restrict__ A,
                                                const bf16* __restrict__ B,
                                                unsigned char* __restrict__ C){
    constexpr int K = FIN, N = F1;
    constexpr int LDT = 40;
    __shared__ __align__(16) bf16 As[128 * LDT];
    __shared__ __align__(16) bf16 Bs[128 * LDT];
    const int t = threadIdx.x;
    const int lane = t & 63, wid = t >> 6;
    const int m0 = blockIdx.x * 128, n0 = blockIdx.y * 128;
    const int r0 = t >> 2, u0 = t & 3;
    const int r1 = r0 + 64;
    const int rb = (wid & 1) * 64, cb = (wid >> 1) * 64;
    const int fr = lane & 15, fk = (lane >> 4) * 8;

    f32x4 acc[4][4];
#pragma unroll
    for (int i = 0; i < 4; i++)
#pragma unroll
        for (int j = 0; j < 4; j++) acc[i][j] = (f32x4)(0.f);

    for (int k0 = 0; k0 < K; k0 += 32){
        const int ga0 = m0 + r0, ga1 = m0 + r1;
        float4 a0a = make_float4(0,0,0,0), a0b = a0a, a1a = a0a, a1b = a0a;
        if (ga0 < NN){
            const float* p = A + (size_t)ga0 * K + k0 + u0 * 8;
            a0a = *(const float4*)p; a0b = *(const float4*)(p + 4);
        }
        if (ga1 < NN){
            const float* p = A + (size_t)ga1 * K + k0 + u0 * 8;
            a1a = *(const float4*)p; a1b = *(const float4*)(p + 4);
        }
        uint4 av0, av1;
        av0.x = bpack(a0a.x, a0a.y); av0.y = bpack(a0a.z, a0a.w);
        av0.z = bpack(a0b.x, a0b.y); av0.w = bpack(a0b.z, a0b.w);
        av1.x = bpack(a1a.x, a1a.y); av1.y = bpack(a1a.z, a1a.w);
        av1.z = bpack(a1b.x, a1b.y); av1.w = bpack(a1b.z, a1b.w);
        uint4 bv0 = *(const uint4*)(B + (size_t)(n0 + r0) * K + k0 + u0 * 8);
        uint4 bv1 = *(const uint4*)(B + (size_t)(n0 + r1) * K + k0 + u0 * 8);
        __syncthreads();
        *(uint4*)(As + r0 * LDT + u0 * 8) = av0;
        *(uint4*)(As + r1 * LDT + u0 * 8) = av1;
        *(uint4*)(Bs + r0 * LDT + u0 * 8) = bv0;
        *(uint4*)(Bs + r1 * LDT + u0 * 8) = bv1;
        __syncthreads();
        short8 af[4], bf_[4];
#pragma unroll
        for (int i = 0; i < 4; i++){
            af[i]  = *(const short8*)(As + (rb + i * 16 + fr) * LDT + fk);
            bf_[i] = *(const short8*)(Bs + (cb + i * 16 + fr) * LDT + fk);
        }
#pragma unroll
        for (int i = 0; i < 4; i++)
#pragma unroll
            for (int j = 0; j < 4; j++)
                acc[i][j] = __builtin_amdgcn_mfma_f32_16x16x32_bf16(af[i], bf_[j], acc[i][j], 0, 0, 0);
    }
    const int crow = m0 + rb + (lane >> 4) * 4;
    const int ccol = n0 + cb + (lane & 15);
#pragma unroll
    for (int i = 0; i < 4; i++)
#pragma unroll
        for (int j = 0; j < 4; j++)
#pragma unroll
            for (int v = 0; v < 4; v++){
                int row = crow + i * 16 + v;
                if (row < NN){
                    float val = acc[i][j][v];
                    unsigned r = __builtin_amdgcn_cvt_pk_fp8_f32(val, val, 0u, false);
                    C[(size_t)row * N + ccol + j * 16] = (unsigned char)(r & 0xffu);
                }
            }
}

// ---------------- GEMM2: 64x128 tile (782 blocks), bf16 A, fp8 out ----------------
__global__ __launch_bounds__(256) void k_gemm2n(const bf16* __restrict__ A,
                                                const bf16* __restrict__ B,
                                                unsigned char* __restrict__ C){
    constexpr int K = F1, N = EMB;
    constexpr int LDT = 40;
    __shared__ __align__(16) bf16 As[64 * LDT];
    __shared__ __align__(16) bf16 Bs[128 * LDT];
    const int t = threadIdx.x;
    const int lane = t & 63, wid = t >> 6;
    const int m0 = blockIdx.x * 64;
    const int r = t >> 2, u0 = t & 3;     // A row 0..63 / B row r and r+64
    const int rb = (wid & 1) * 32, cb = (wid >> 1) * 64;
    const int fr = lane & 15, fk = (lane >> 4) * 8;

    f32x4 acc[2][4];
#pragma unroll
    for (int i = 0; i < 2; i++)
#pragma unroll
        for (int j = 0; j < 4; j++) acc[i][j] = (f32x4)(0.f);

    for (int k0 = 0; k0 < K; k0 += 32){
        const int ga = m0 + r;
        uint4 av = (ga < NN) ? *(const uint4*)(A + (size_t)ga * K + k0 + u0 * 8)
                             : make_uint4(0, 0, 0, 0);
        uint4 bv0 = *(const uint4*)(B + (size_t)r * K + k0 + u0 * 8);
        uint4 bv1 = *(const uint4*)(B + (size_t)(r + 64) * K + k0 + u0 * 8);
        __syncthreads();
        *(uint4*)(As + r * LDT + u0 * 8) = av;
        *(uint4*)(Bs + r * LDT + u0 * 8) = bv0;
        *(uint4*)(Bs + (r + 64) * LDT + u0 * 8) = bv1;
        __syncthreads();
        short8 af[2], bf_[4];
#pragma unroll
        for (int i = 0; i < 2; i++)
            af[i] = *(const short8*)(As + (rb + i * 16 + fr) * LDT + fk);
#pragma unroll
        for (int j = 0; j < 4; j++)
            bf_[j] = *(const short8*)(Bs + (cb + j * 16 + fr) * LDT + fk);
#pragma unroll
        for (int i = 0; i < 2; i++)
#pragma unroll
            for (int j = 0; j < 4; j++)
                acc[i][j] = __builtin_amdgcn_mfma_f32_16x16x32_bf16(af[i], bf_[j], acc[i][j], 0, 0, 0);
    }
    const int crow = m0 + rb + (lane >> 4) * 4;
    const int ccol = cb + (lane & 15);
#pragma unroll
    for (int i = 0; i < 2; i++)
#pragma unroll
        for (int j = 0; j < 4; j++)
#pragma unroll
            for (int v = 0; v < 4; v++){
                int row = crow + i * 16 + v;
                if (row < NN){
                    float val = acc[i][j][v];
                    unsigned r8 = __builtin_amdgcn_cvt_pk_fp8_f32(val, val, 0u, false);
                    C[(size_t)row * N + ccol + j * 16] = (unsigned char)(r8 & 0xffu);
                }
            }
}

// ---------------- fused: layer-1 scalars + fp4 payload encode (streamed, low VGPR) ----
__global__ void k_s1q(const unsigned char* __restrict__ h1q, const float* __restrict__ a1,
                      float* __restrict__ s11, float* __restrict__ s12,
                      unsigned char* __restrict__ pay){
    int idx = blockIdx.x * 256 + threadIdx.x;
    if (idx >= NN * NH) return;
    int n = idx >> 3, h = idx & 7;
    const uint4* hp = (const uint4*)(h1q + (size_t)n * F1 + h * HID);
    const float* a  = a1 + (size_t)h * 2 * HID;
    float d1 = 0.f, d2 = 0.f;
#if HAVE_FP4
    unsigned w8[8];
#endif
#pragma unroll
    for (int u = 0; u < 4; u++){
        uint4 q = hp[u];
        int j = u * 16;
        f32x2 p0 = __builtin_amdgcn_cvt_pk_f32_fp8(q.x, false);
        f32x2 p1 = __builtin_amdgcn_cvt_pk_f32_fp8(q.x, true);
        f32x2 p2 = __builtin_amdgcn_cvt_pk_f32_fp8(q.y, false);
        f32x2 p3 = __builtin_amdgcn_cvt_pk_f32_fp8(q.y, true);
        f32x2 p4 = __builtin_amdgcn_cvt_pk_f32_fp8(q.z, false);
        f32x2 p5 = __builtin_amdgcn_cvt_pk_f32_fp8(q.z, true);
        f32x2 p6 = __builtin_amdgcn_cvt_pk_f32_fp8(q.w, false);
        f32x2 p7 = __builtin_amdgcn_cvt_pk_f32_fp8(q.w, true);
        d1 += p0[0]*a[j+0] + p0[1]*a[j+1] + p1[0]*a[j+2] + p1[1]*a[j+3]
            + p2[0]*a[j+4] + p2[1]*a[j+5] + p3[0]*a[j+6] + p3[1]*a[j+7]
            + p4[0]*a[j+8] + p4[1]*a[j+9] + p5[0]*a[j+10]+ p5[1]*a[j+11]
            + p6[0]*a[j+12]+ p6[1]*a[j+13]+ p7[0]*a[j+14]+ p7[1]*a[j+15];
        d2 += p0[0]*a[HID+j+0] + p0[1]*a[HID+j+1] + p1[0]*a[HID+j+2] + p1[1]*a[HID+j+3]
            + p2[0]*a[HID+j+4] + p2[1]*a[HID+j+5] + p3[0]*a[HID+j+6] + p3[1]*a[HID+j+7]
            + p4[0]*a[HID+j+8] + p4[1]*a[HID+j+9] + p5[0]*a[HID+j+10]+ p5[1]*a[HID+j+11]
            + p6[0]*a[HID+j+12]+ p6[1]*a[HID+j+13]+ p7[0]*a[HID+j+14]+ p7[1]*a[HID+j+15];
#if HAVE_FP4
        unsigned r0 = 0, r1 = 0;
        r0 = __builtin_amdgcn_cvt_scalef32_pk_fp4_f32(r0, p0[0]*SINV1, p0[1]*SINV1, 1.0f, 0);
        r0 = __builtin_amdgcn_cvt_scalef32_pk_fp4_f32(r0, p1[0]*SINV1, p1[1]*SINV1, 1.0f, 1);
        r0 = __builtin_amdgcn_cvt_scalef32_pk_fp4_f32(r0, p2[0]*SINV1, p2[1]*SINV1, 1.0f, 2);
        r0 = __builtin_amdgcn_cvt_scalef32_pk_fp4_f32(r0, p3[0]*SINV1, p3[1]*SINV1, 1.0f, 3);
        r1 = __builtin_amdgcn_cvt_scalef32_pk_fp4_f32(r1, p4[0]*SINV1, p4[1]*SINV1, 1.0f, 0);
        r1 = __builtin_amdgcn_cvt_scalef32_pk_fp4_f32(r1, p5[0]*SINV1, p5[1]*SINV1, 1.0f, 1);
        r1 = __builtin_amdgcn_cvt_scalef32_pk_fp4_f32(r1, p6[0]*SINV1, p6[1]*SINV1, 1.0f, 2);
        r1 = __builtin_amdgcn_cvt_scalef32_pk_fp4_f32(r1, p7[0]*SINV1, p7[1]*SINV1, 1.0f, 3);
        w8[2 * u] = r0; w8[2 * u + 1] = r1;
#endif
    }
    s11[idx] = d1;
    s12[idx] = d2;
#if HAVE_FP4
    uint4* op = (uint4*)(pay + (size_t)n * PAYB1 + h * (HID / 2));
    uint4 o0, o1;
    o0.x = w8[0]; o0.y = w8[1]; o0.z = w8[2]; o0.w = w8[3];
    o1.x = w8[4]; o1.y = w8[5]; o1.z = w8[6]; o1.w = w8[7];
    op[0] = o0; op[1] = o1;
#else
    uint4* op = (uint4*)(pay + (size_t)n * PAYB1 + h * HID);
    op[0] = hp[0]; op[1] = hp[1]; op[2] = hp[2]; op[3] = hp[3];
#endif
}

// ---------------- layer-1 aggregation (unchanged structure) ----------
__global__ __launch_bounds__(256) void k_agg1(const unsigned char* __restrict__ hq,
                                              const unsigned short* __restrict__ ee8b,
                                              const int* __restrict__ rp,
                                              const int* __restrict__ sdst,
                                              bf16* __restrict__ x1){
    const int t = threadIdx.x, lane = t & 63, w = t >> 6;
    const int n = blockIdx.x * 4 + w;
    const int l32 = lane & 31;
    const int half = lane >> 5;
    const int hf = l32 >> 2;
    const int eslot = lane >> 3;
    f32x2 acc[8];
#pragma unroll
    for (int i = 0; i < 8; i++){ acc[i][0] = 0.f; acc[i][1] = 0.f; }
    float dedp = 0.f;
    const int start = rp[n], end = rp[n + 1];
    const unsigned char* __restrict__ hl = hq + (size_t)l32 * (PAYB1 / 32);
    for (int c0 = start; c0 < end; c0 += 64){
        const int m = min(64, end - c0);
        int dreg = (lane < m) ? sdst[c0 + lane] : 0;
        for (int g = 0; g * 8 < m; g++){
            unsigned short eu = ee8b[(size_t)(c0 + g * 8) * 8 + lane];
            dedp += (g * 8 + eslot < m) ? b2f(eu) : 0.f;
        }
        for (int j = 0; j < m; j += 16){
            int dj[8]; unsigned short eu[8]; pay_t q[8];
#pragma unroll
            for (int p = 0; p < 8; p++){
                const int e2 = j + 2 * p + half;
                dj[p] = __shfl(dreg, e2);
                eu[p] = ee8b[(size_t)(c0 + e2) * 8 + hf];
                q[p]  = *(const pay_t*)(hl + (size_t)dj[p] * PAYB1);
            }
#pragma unroll
            for (int p = 0; p < 8; p++){
                const int e2 = j + 2 * p + half;
                const float e = (e2 < m) ? b2f(eu[p]) : 0.f;
                fma16pk(acc, q[p], e);
            }
        }
    }
    dedp += __shfl_xor(dedp, 8);
    dedp += __shfl_xor(dedp, 16);
    dedp += __shfl_xor(dedp, 32);
#pragma unroll
    for (int i = 0; i < 8; i++){
        acc[i][0] += __shfl_xor(acc[i][0], 32);
        acc[i][1] += __shfl_xor(acc[i][1], 32);
    }
    float ded = __shfl(dedp, hf);
    const float inv = PSC1 / (ded + EPSF);
    if (half == 0){
        float o[16];
#pragma unroll
        for (int i = 0; i < 8; i++){
            o[2 * i]     = eluf(acc[i][0] * inv);
            o[2 * i + 1] = eluf(acc[i][1] * inv);
        }
        uint4 ov0, ov1;
        ov0.x = bpack(o[0], o[1]);   ov0.y = bpack(o[2], o[3]);
        ov0.z = bpack(o[4], o[5]);   ov0.w = bpack(o[6], o[7]);
        ov1.x = bpack(o[8], o[9]);   ov1.y = bpack(o[10], o[11]);
        ov1.z = bpack(o[12], o[13]); ov1.w = bpack(o[14], o[15]);
        bf16* xp = x1 + (size_t)n * F1 + l32 * 16;
        *(uint4*)xp = ov0;
        *(uint4*)(xp + 8) = ov1;
    }
}

// ---------------- per-node attention scalars, layer 2 (fp8 h2) ----------------
__global__ void k_s2(const unsigned char* __restrict__ h2q, const float* __restrict__ ao,
                     float* __restrict__ s21, float* __restrict__ s22){
    int n = blockIdx.x * 256 + threadIdx.x;
    if (n >= NN) return;
    const uint4* hp = (const uint4*)(h2q + (size_t)n * EMB);
    float d1 = 0.f, d2 = 0.f;
#pragma unroll
    for (int u = 0; u < 8; u++){
        uint4 q = hp[u];
        int j = u * 16;
#define S2(w, o) { f32x2 p0 = __builtin_amdgcn_cvt_pk_f32_fp8((w), false); \
                   f32x2 p1 = __builtin_amdgcn_cvt_pk_f32_fp8((w), true); \
                   d1 += p0[0]*ao[(o)] + p0[1]*ao[(o)+1] + p1[0]*ao[(o)+2] + p1[1]*ao[(o)+3]; \
                   d2 += p0[0]*ao[EMB+(o)] + p0[1]*ao[EMB+(o)+1] + p1[0]*ao[EMB+(o)+2] + p1[1]*ao[EMB+(o)+3]; }
        S2(q.x, j) S2(q.y, j + 4) S2(q.z, j + 8) S2(q.w, j + 12)
#undef S2
    }
    s21[n] = d1;
    s22[n] = d2;
}

// ---------------- layer-2 aggregation: ee2 precomputed, flattened chain ----------
__global__ __launch_bounds__(256) void k_agg2(const unsigned char* __restrict__ hq,
                                              const float* __restrict__ ee2,
                                              const int* __restrict__ rp,
                                              const int* __restrict__ sdst,
                                              float* __restrict__ den2,
                                              float* __restrict__ out0){
    const int t = threadIdx.x, lane = t & 63, w = t >> 6;
    const int n = blockIdx.x * 4 + w;
    const int slot = lane >> 3;
    const int fpos = lane & 7;
    f32x2 acc[8];
#pragma unroll
    for (int i = 0; i < 8; i++){ acc[i][0] = 0.f; acc[i][1] = 0.f; }
    float dedp = 0.f;
    const int start = rp[n], end = rp[n + 1];
    const unsigned char* __restrict__ hl = hq + (size_t)fpos * (PAYB2 / 8);
    for (int c0 = start; c0 < end; c0 += 64){
        const int m = min(64, end - c0);
        int dreg = (lane < m) ? sdst[c0 + lane] : 0;
        float ev = (lane < m) ? ee2[c0 + lane] : 0.f;
        dedp += ev;
        for (int j = 0; j < m; j += 8){
            const int ei = j + slot;
            const float e = __shfl(ev, ei);
            const int   d = __shfl(dreg, ei);
            pay_t q = *(const pay_t*)(hl + (size_t)d * PAYB2);
            fma16pk(acc, q, e);
        }
    }
#pragma unroll
    for (int o = 1; o <= 32; o <<= 1) dedp += __shfl_xor(dedp, o);
#pragma unroll
    for (int o = 8; o <= 32; o <<= 1)
#pragma unroll
        for (int i = 0; i < 8; i++){
            acc[i][0] += __shfl_xor(acc[i][0], o);
            acc[i][1] += __shfl_xor(acc[i][1], o);
        }
    const float den = dedp + EPSF;
    if (slot == 0){
        const float inv = PSC2 / den;
        float* op = out0 + (size_t)n * EMB + fpos * 16;
#pragma unroll
        for (int u = 0; u < 4; u++){
            float4 ov;
            ov.x = eluf(acc[2 * u][0] * inv);
            ov.y = eluf(acc[2 * u][1] * inv);
            ov.z = eluf(acc[2 * u + 1][0] * inv);
            ov.w = eluf(acc[2 * u + 1][1] * inv);
            *(float4*)(op + u * 4) = ov;
        }
        if (lane == 0) den2[n] = den;
    }
}

// ---------------- fused, vectorized x4: edge_index copy + att_out ----------------
__global__ void k_att_edge4(const int* __restrict__ ei,
                            const float* __restrict__ s21, const float* __restrict__ s22,
                            const float* __restrict__ den2,
                            float* __restrict__ outE, float* __restrict__ outA){
    int i = blockIdx.x * 256 + threadIdx.x;
    if (i >= NE / 4) return;
    int4 s4 = ((const int4*)ei)[i];
    int4 d4 = ((const int4*)(ei + NE))[i];
    float4 fs = make_float4((float)s4.x, (float)s4.y, (float)s4.z, (float)s4.w);
    float4 fd = make_float4((float)d4.x, (float)d4.y, (float)d4.z, (float)d4.w);
    ((float4*)outE)[i] = fs;
    ((float4*)(outE + NE))[i] = fd;
    float4 av;
    av.x = lrelu_neg_exp(s21[s4.x] + s22[d4.x]) / den2[s4.x];
    av.y = lrelu_neg_exp(s21[s4.y] + s22[d4.y]) / den2[s4.y];
    av.z = lrelu_neg_exp(s21[s4.z] + s22[d4.z]) / den2[s4.z];
    av.w = lrelu_neg_exp(s21[s4.w] + s22[d4.w]) / den2[s4.w];
    ((float4*)outA)[i] = av;
}

// ---------------- launch ----------------
extern "C" void kernel_launch(void* const* d_in, const int* in_sizes, int n_in,
                              void* d_out, int out_size, void* d_ws, size_t ws_size,
                              hipStream_t stream){
    const float* x  = (const float*)d_in[0];
    const int*   ei = (const int*)d_in[1];
    const float* W1 = (const float*)d_in[2];
    const float* a1 = (const float*)d_in[3];
    const float* Wo = (const float*)d_in[4];
    const float* ao = (const float*)d_in[5];
    float* out = (float*)d_out;
    const int* src = ei;
    const int* dst = ei + NE;

    char* w = (char*)d_ws;
    auto alloc = [&](size_t bytes) -> char* {
        char* p = w;
        w += (bytes + 255) & ~(size_t)255;
        return p;
    };
    unsigned char* h1pay = (unsigned char*)alloc((size_t)NN * F1);       // 25.6 MB
    bf16*  x1   = (bf16*) alloc((size_t)NN * F1 * 2);                    // 51.2 MB
    unsigned char* h1q = (unsigned char*)alloc((size_t)NN * F1);         // 25.6 MB
    unsigned char* h2q = (unsigned char*)alloc((size_t)NN * EMB);        // 6.4 MB
    unsigned short* ee8b = (unsigned short*)alloc(((size_t)NE + 64) * 8 * 2); // 12.8 MB
    float* ee2  = (float*)alloc((size_t)NE * 4);                         // 3.2 MB
    bf16*  Bt1  = (bf16*) alloc((size_t)F1 * FIN * 2);
    bf16*  WoT  = (bf16*) alloc((size_t)EMB * F1 * 2);
    float* s11  = (float*)alloc((size_t)NN * NH * 4);
    float* s12  = (float*)alloc((size_t)NN * NH * 4);
    float* s21  = (float*)alloc((size_t)NN * 4);
    float* s22  = (float*)alloc((size_t)NN * 4);
    float* den2 = (float*)alloc((size_t)NN * 4);
    int*   cnt2 = (int*)  alloc((size_t)2 * NN * 4);
    int*   rp   = (int*)  alloc((size_t)(NN + 1) * 4);
    int*   sdst = (int*)  alloc((size_t)NE * 4);
    int*   ssrc = (int*)  alloc((size_t)NE * 4);
    int*   bsum = (int*)  alloc((size_t)NBLK * 4);
    int*   boff = (int*)  alloc((size_t)NBLK * 4);
    int*   cnt = cnt2;
    int*   cur = cnt2 + NN;
    unsigned char* h2pay = (unsigned char*)x1;   // x1 dead after gemm2

    // weight transposes
    k_tw1<<<(F1 * FIN + 255) / 256, 256, 0, stream>>>(W1, Bt1);
    k_tw2<<<(EMB * F1 + 255) / 256, 256, 0, stream>>>(Wo, WoT);

    // CSR counts + row pointers
    k_zero <<<(2 * NN + 255) / 256, 256, 0, stream>>>(cnt2, 2 * NN);
    k_count<<<(NE + 255) / 256,     256, 0, stream>>>(src, cnt);
    k_bsum <<<NBLK,                 256, 0, stream>>>(cnt, bsum);
    k_scanb<<<1,                    256, 0, stream>>>(bsum, boff, rp);
    k_rp   <<<NBLK,                 256, 0, stream>>>(cnt, boff, rp);

    // layer 1 compute
    k_gemm1f<<<dim3((NN + 127) / 128, F1 / 128), 256, 0, stream>>>(x, Bt1, h1q);
    k_s1q <<<(NN * NH + 255) / 256, 256, 0, stream>>>(h1q, a1, s11, s12, h1pay);
    // scatter fused with layer-1 edge weights (needs s11/s12)
    k_scatter_ee<<<(NE + 255) / 256, 256, 0, stream>>>(src, dst, rp, cur, s11, s12,
                                                       sdst, ssrc, ee8b);
    k_agg1<<<NN / 4, 256, 0, stream>>>(h1pay, ee8b, rp, sdst, x1);

    // layer 2
    k_gemm2n<<<(NN + 63) / 64, 256, 0, stream>>>(x1, WoT, h2q);
    k_q4  <<<(NN * EMB / 8 + 255) / 256, 256, 0, stream>>>(h2q, (unsigned*)h2pay, NN * EMB / 8, SINV2);
    k_s2  <<<(NN + 255) / 256, 256, 0, stream>>>(h2q, ao, s21, s22);
    k_ee2 <<<(NE + 255) / 256, 256, 0, stream>>>(ssrc, sdst, s21, s22, ee2);
    k_agg2<<<NN / 4, 256, 0, stream>>>(h2pay, ee2, rp, sdst, den2, out);

    // outputs 1 & 2
    k_att_edge4<<<(NE / 4 + 255) / 256, 256, 0, stream>>>(ei, s21, s22, den2,
                                                          out + (size_t)NN * EMB,
                                                          out + (size_t)NN * EMB + 2 * NE);
}